// Round 8
// baseline (95.062 us; speedup 1.0000x reference)
//
#include <hip/hip_runtime.h>
#include <hip/hip_bf16.h>
#include <stdint.h>

// ---------------- problem constants ----------------
#define BATCH  4096
#define IN_DIM 1024
#define HS     1024
#define K_DIM  2048                 // IN + HS
#define N_DIM  4096                 // 4 gates * HS (gate-interleaved, see pack)
#define BK 64
#define NKT (K_DIM / BK)            // 32 K-tiles
#define HALF_BYTES 16384            // 128 rows x 64 cols x 2B
#define TPB_BYTES  (NKT * HALF_BYTES)   // bytes per 128-row panel, all K

typedef __bf16 bf16x8 __attribute__((ext_vector_type(8)));
typedef float  f32x4  __attribute__((ext_vector_type(4)));

// ---------------- helpers ----------------
__device__ __forceinline__ unsigned short f2bf(float f) {
    union { float f; uint32_t u; } a; a.f = f;
    uint32_t r = a.u + 0x7FFF + ((a.u >> 16) & 1);   // RNE
    return (unsigned short)(r >> 16);
}
__device__ __forceinline__ uint32_t pk2(float a, float b) {
    return (uint32_t)f2bf(a) | ((uint32_t)f2bf(b) << 16);
}

__device__ __forceinline__ void load16_lds(const void* g, void* l) {
    __builtin_amdgcn_global_load_lds(
        (const __attribute__((address_space(1))) uint32_t*)g,
        (__attribute__((address_space(3))) uint32_t*)(uintptr_t)l,
        16, 0, 0);
}
// stage one 16KB half-tile: 512 threads x 16B x 2 rounds (2 vmem insts)
__device__ __forceinline__ void stage16k(const char* g, char* l, int wid, int lane) {
    load16_lds(g + wid * 1024 + lane * 16,        l + wid * 1024);
    load16_lds(g + 8192 + wid * 1024 + lane * 16, l + 8192 + wid * 1024);
}

__device__ __forceinline__ float sigf(float x)  { return 1.0f / (1.0f + __expf(-x)); }
__device__ __forceinline__ float tanhf_(float x){ return 1.0f - 2.0f / (__expf(2.0f * x) + 1.0f); }

#define BAR()   __builtin_amdgcn_s_barrier()
#define PRIO(x) __builtin_amdgcn_s_setprio(x)
#define VMC0()  asm volatile("s_waitcnt vmcnt(0)" ::: "memory")

// 4 A-reads of one 32-row quad: d[mf*2+ks]
__device__ __forceinline__ void rdA4(bf16x8 (&d)[4], const char* base, int kb0, int kb1) {
    d[0] = *(const bf16x8*)(base + kb0);
    d[1] = *(const bf16x8*)(base + kb1);
    d[2] = *(const bf16x8*)(base + 2048 + kb0);
    d[3] = *(const bf16x8*)(base + 2048 + kb1);
}
// 8 B-reads of the wave's 64-col x 64-k B-slice: d[ks*4+j]
__device__ __forceinline__ void rdB8(bf16x8 (&d)[8], const char* base, int kb0, int kb1) {
    #pragma unroll
    for (int j = 0; j < 4; ++j) {
        d[j]     = *(const bf16x8*)(base + j * 2048 + kb0);
        d[4 + j] = *(const bf16x8*)(base + j * 2048 + kb1);
    }
}
// 16 MFMA for quadrant Q (rows [Q*32, Q*32+32) of the wave tile)
template<int Q>
__device__ __forceinline__ void mfq(f32x4 (&acc)[8][4], const bf16x8 (&a)[4],
                                    const bf16x8 (&b)[8]) {
    #pragma unroll
    for (int mf = 0; mf < 2; ++mf)
        #pragma unroll
        for (int ks = 0; ks < 2; ++ks)
            #pragma unroll
            for (int j = 0; j < 4; ++j)
                acc[2 * Q + mf][j] = __builtin_amdgcn_mfma_f32_16x16x32_bf16(
                    a[mf * 2 + ks], b[ks * 4 + j], acc[2 * Q + mf][j], 0, 0, 0);
}

// ---------------- kernel 1: pack A=[x|h], B gate-INTERLEAVED (unchanged) ----
__global__ void pack_kernel(const float* __restrict__ x, const float* __restrict__ h,
                            const float* __restrict__ Wix, const float* __restrict__ Wfx,
                            const float* __restrict__ Wgx, const float* __restrict__ Wox,
                            const float* __restrict__ Wih, const float* __restrict__ Wfh,
                            const float* __restrict__ Wgh, const float* __restrict__ Woh,
                            uint4* __restrict__ Apk, uint4* __restrict__ Bpk)
{
    int t = blockIdx.x * blockDim.x + threadIdx.x;     // 0 .. 2M-1
    const int NCHUNK = (BATCH * K_DIM) / 8;            // 1,048,576 chunks / matrix
    bool isB = t >= NCHUNK;
    int ci = isB ? (t - NCHUNK) : t;

    int cb  = ci & 7;              // 16B chunk within row (8 bf16)
    int row = (ci >> 3) & 127;     // row within 128-row panel
    int kt  = (ci >> 10) & 31;     // K-tile
    int bt  = ci >> 15;            // 128-row panel index, 0..31

    // inverse swizzle: chunk cb of LDS row holds source chunk cb ^ (row&7)
    int k0 = kt * BK + ((cb ^ (row & 7)) << 3);        // source k element, %8==0
    int gr = bt * 128 + row;                           // global m or packed col n'

    const float* src;
    if (!isB) {
        src = (k0 < IN_DIM) ? (x + (size_t)gr * IN_DIM + k0)
                            : (h + (size_t)gr * HS + (k0 - IN_DIM));
    } else {
        int q = (gr >> 4) & 3;                         // gate
        int u = ((gr >> 6) << 4) | (gr & 15);          // unit
        const float* Wq = (k0 < IN_DIM)
            ? ((q == 0) ? Wix : (q == 1) ? Wfx : (q == 2) ? Wgx : Wox)
            : ((q == 0) ? Wih : (q == 1) ? Wfh : (q == 2) ? Wgh : Woh);
        int kk = (k0 < IN_DIM) ? k0 : (k0 - IN_DIM);
        src = Wq + (size_t)u * 1024 + kk;
    }
    float4 v0 = ((const float4*)src)[0];
    float4 v1 = ((const float4*)src)[1];
    uint4 o;
    o.x = pk2(v0.x, v0.y); o.y = pk2(v0.z, v0.w);
    o.z = pk2(v1.x, v1.y); o.w = pk2(v1.z, v1.w);
    (isB ? Bpk : Apk)[ci] = o;
}

// ---------------- kernel 2: fused GEMM + LSTM gates ----------------
// 256x256 tile, 8 waves (2Mx4N). MINIMAL-BARRIER double-buffer: exactly one
// vmcnt(0)+s_barrier per K-tile. Tile body: [VMC0+BAR: buf[t&1] staged &
// visible, other buf free] -> issue stage(t+1) into other buf (drains over a
// full ~5000-cyc tile, so next tile's vmcnt(0) is nearly free) -> rdB8 +
// 4x(rdA4 -> 16 MFMA), NO manual lgkm / sched fences: the compiler emits
// counted lgkm waits and the 2 waves/SIMD drift apart between barriers,
// overlapping one wave's ds_read drain with the other's MFMA cluster
// (the per-phase barriers of r2..r7 prevented exactly this drift).
// WAR-safety: stage(t+1)->Ln issues after BAR(t); every wave's reads of Ln
// (tile t-1) completed before its own tile-(t-1) MFMAs, hence before BAR(t).
// Last tile peeled: c/bias prefetch issues first (hides HBM latency under
// the final tile's compute), no further staging.
__global__ void __launch_bounds__(512, 2)
gemm_kernel(const char* __restrict__ Apk, const char* __restrict__ Bpk,
            const float* __restrict__ c,
            const float* __restrict__ bix, const float* __restrict__ bfx,
            const float* __restrict__ bgx, const float* __restrict__ box_,
            const float* __restrict__ bih, const float* __restrict__ bfh,
            const float* __restrict__ bgh, const float* __restrict__ boh,
            float* __restrict__ out)
{
    __shared__ uint4 lds4[131072 / 16];                // 128 KiB
    char* lds = (char*)lds4;

    const int tid  = threadIdx.x;
    const int lane = tid & 63;
    const int wid  = tid >> 6;       // 0..7
    const int wm   = wid >> 2;       // 0..1
    const int wn   = wid & 3;        // 0..3
    const int fr   = lane & 15;
    const int kg   = lane >> 4;

    // XCD-aware bijective swizzle: 256 blocks, 8 XCDs, 32 blocks/XCD chunk
    const int phys = blockIdx.x;
    const int virt = (phys & 7) * 32 + (phys >> 3);
    const int bn   = virt & 15;
    const int bm   = virt >> 4;

    const char* gA = Apk + (size_t)(bm * 2) * TPB_BYTES;
    const char* gB = Bpk + (size_t)(bn * 2) * TPB_BYTES;

    // ds_read addressing (swizzle: k-byte ^ ((row&7)<<4); row%8 == fr%8)
    const int kb0   = (kg * 16) ^ ((fr & 7) << 4);
    const int kb1   = kb0 ^ 64;
    const int aOff  = wm * 16384 + fr * 128;           // + q*4096 + mf*2048
    const int bOff  = 32768 + wn * 8192 + fr * 128;    // + j*2048

    f32x4 acc[8][4] = {};
    bf16x8 a0[4], a1[4], a2[4], a3[4], bC[8];

    // ---- prologue: stage tile 0 into buf0 ----
    stage16k(gA + (size_t)(0 * NKT + 0) * HALF_BYTES, lds + 0,     wid, lane);
    stage16k(gA + (size_t)(1 * NKT + 0) * HALF_BYTES, lds + 16384, wid, lane);
    stage16k(gB + (size_t)(0 * NKT + 0) * HALF_BYTES, lds + 32768, wid, lane);
    stage16k(gB + (size_t)(1 * NKT + 0) * HALF_BYTES, lds + 49152, wid, lane);

    for (int t = 0; t < NKT - 1; ++t) {
        char* L  = lds + (t & 1) * 65536;
        char* Ln = lds + ((t & 1) ^ 1) * 65536;
        VMC0();                    // own stages of tile t (issued >=1 tile ago)
        BAR();                     // cross-wave visibility; Ln free for staging
        stage16k(gA + (size_t)(0 * NKT + t + 1) * HALF_BYTES, Ln + 0,     wid, lane);
        stage16k(gA + (size_t)(1 * NKT + t + 1) * HALF_BYTES, Ln + 16384, wid, lane);
        stage16k(gB + (size_t)(0 * NKT + t + 1) * HALF_BYTES, Ln + 32768, wid, lane);
        stage16k(gB + (size_t)(1 * NKT + t + 1) * HALF_BYTES, Ln + 49152, wid, lane);
        rdB8(bC, L + bOff, kb0, kb1);
        rdA4(a0, L + aOff,         kb0, kb1);
        rdA4(a1, L + aOff + 4096,  kb0, kb1);
        PRIO(1); mfq<0>(acc, a0, bC); PRIO(0);
        rdA4(a2, L + aOff + 8192,  kb0, kb1);
        PRIO(1); mfq<1>(acc, a1, bC); PRIO(0);
        rdA4(a3, L + aOff + 12288, kb0, kb1);
        PRIO(1); mfq<2>(acc, a2, bC); PRIO(0);
        PRIO(1); mfq<3>(acc, a3, bC); PRIO(0);
    }

    // ---- peeled last tile: prefetch c + biases first (hide under compute) --
    const int u  = bn * 64 + wn * 16 + fr;             // unit 0..1023
    const int r0 = bm * 256 + wm * 128;                // batch row base
    {
        char* L = lds + ((NKT - 1) & 1) * 65536;
        VMC0();
        BAR();
        float cpre[8][4];
        #pragma unroll
        for (int ai = 0; ai < 8; ++ai) {
            const int rowb = r0 + ai * 16 + kg * 4;
            #pragma unroll
            for (int r = 0; r < 4; ++r)
                cpre[ai][r] = c[(size_t)(rowb + r) * HS + u];
        }
        const float bi = bix[u] + bih[u];
        const float bf = bfx[u] + bfh[u];
        const float bg = bgx[u] + bgh[u];
        const float bo = box_[u] + boh[u];

        rdB8(bC, L + bOff, kb0, kb1);
        rdA4(a0, L + aOff,         kb0, kb1);
        rdA4(a1, L + aOff + 4096,  kb0, kb1);
        PRIO(1); mfq<0>(acc, a0, bC); PRIO(0);
        rdA4(a2, L + aOff + 8192,  kb0, kb1);
        PRIO(1); mfq<1>(acc, a1, bC); PRIO(0);
        rdA4(a3, L + aOff + 12288, kb0, kb1);
        PRIO(1); mfq<2>(acc, a2, bC); PRIO(0);
        PRIO(1); mfq<3>(acc, a3, bC); PRIO(0);

        // ---- fused LSTM epilogue: lane holds all 4 gates of unit u ----
        float* hout = out;
        float* cout = out + (size_t)BATCH * HS;
        #pragma unroll
        for (int ai = 0; ai < 8; ++ai) {
            const int rowb = r0 + ai * 16 + kg * 4;
            #pragma unroll
            for (int r = 0; r < 4; ++r) {
                const size_t idx = (size_t)(rowb + r) * HS + u;
                float iv = sigf  (acc[ai][0][r] + bi);
                float fv = sigf  (acc[ai][1][r] + bf);
                float gv = tanhf_(acc[ai][2][r] + bg);
                float ov = sigf  (acc[ai][3][r] + bo);
                float cn = fv * cpre[ai][r] + iv * gv;
                hout[idx] = ov * tanhf_(cn);
                cout[idx] = cn;
            }
        }
    }
}

// ---------------- launcher ----------------
extern "C" void kernel_launch(void* const* d_in, const int* in_sizes, int n_in,
                              void* d_out, int out_size, void* d_ws, size_t ws_size,
                              hipStream_t stream)
{
    const float* x   = (const float*)d_in[0];
    const float* h   = (const float*)d_in[1];
    const float* c   = (const float*)d_in[2];
    const float* Wix = (const float*)d_in[3];  const float* bix = (const float*)d_in[4];
    const float* Wfx = (const float*)d_in[5];  const float* bfx = (const float*)d_in[6];
    const float* Wgx = (const float*)d_in[7];  const float* bgx = (const float*)d_in[8];
    const float* Wox = (const float*)d_in[9];  const float* box_ = (const float*)d_in[10];
    const float* Wih = (const float*)d_in[11]; const float* bih = (const float*)d_in[12];
    const float* Wfh = (const float*)d_in[13]; const float* bfh = (const float*)d_in[14];
    const float* Wgh = (const float*)d_in[15]; const float* bgh = (const float*)d_in[16];
    const float* Woh = (const float*)d_in[17]; const float* boh = (const float*)d_in[18];

    char* ws = (char*)d_ws;
    uint4* Apk = (uint4*)ws;                                   // 16 MB
    uint4* Bpk = (uint4*)(ws + (size_t)16 * 1024 * 1024);      // 16 MB

    pack_kernel<<<8192, 256, 0, stream>>>(x, h, Wix, Wfx, Wgx, Wox,
                                          Wih, Wfh, Wgh, Woh, Apk, Bpk);
    gemm_kernel<<<256, 512, 0, stream>>>((const char*)Apk, (const char*)Bpk, c,
                                         bix, bfx, bgx, box_, bih, bfh, bgh, boh,
                                         (float*)d_out);
}

// Round 9
// 84.377 us; speedup vs baseline: 1.1266x; 1.1266x over previous
//
#include <hip/hip_runtime.h>
#include <hip/hip_bf16.h>
#include <stdint.h>

// ---------------- problem constants ----------------
#define BATCH  4096
#define IN_DIM 1024
#define HS     1024
#define K_DIM  2048                 // IN + HS
#define N_DIM  4096                 // 4 gates * HS (gate-interleaved, see pack)
#define BK 64
#define NKT (K_DIM / BK)            // 32 K-tiles
#define HALF_BYTES 16384            // 128 rows x 64 cols x 2B
#define TPB_BYTES  (NKT * HALF_BYTES)   // bytes per 128-row panel, all K

typedef __bf16 bf16x8 __attribute__((ext_vector_type(8)));
typedef float  f32x4  __attribute__((ext_vector_type(4)));

// ---------------- helpers ----------------
__device__ __forceinline__ unsigned short f2bf(float f) {
    union { float f; uint32_t u; } a; a.f = f;
    uint32_t r = a.u + 0x7FFF + ((a.u >> 16) & 1);   // RNE
    return (unsigned short)(r >> 16);
}
__device__ __forceinline__ uint32_t pk2(float a, float b) {
    return (uint32_t)f2bf(a) | ((uint32_t)f2bf(b) << 16);
}

__device__ __forceinline__ void load16_lds(const void* g, void* l) {
    __builtin_amdgcn_global_load_lds(
        (const __attribute__((address_space(1))) uint32_t*)g,
        (__attribute__((address_space(3))) uint32_t*)(uintptr_t)l,
        16, 0, 0);
}
// stage one 16KB half-tile: 512 threads x 16B x 2 rounds (2 vmem insts)
__device__ __forceinline__ void stage16k(const char* g, char* l, int wid, int lane) {
    load16_lds(g + wid * 1024 + lane * 16,        l + wid * 1024);
    load16_lds(g + 8192 + wid * 1024 + lane * 16, l + 8192 + wid * 1024);
}

__device__ __forceinline__ float sigf(float x)  { return 1.0f / (1.0f + __expf(-x)); }
__device__ __forceinline__ float tanhf_(float x){ return 1.0f - 2.0f / (__expf(2.0f * x) + 1.0f); }

#define BAR()   __builtin_amdgcn_s_barrier()
#define DSB()   __builtin_amdgcn_sched_barrier(0)
#define PRIO(x) __builtin_amdgcn_s_setprio(x)
#define LGKM0() do { asm volatile("s_waitcnt lgkmcnt(0)" ::: "memory"); \
                     __builtin_amdgcn_sched_barrier(0); } while (0)
#define VMC(n)  asm volatile("s_waitcnt vmcnt(" #n ")" ::: "memory")

__device__ __forceinline__ void rdA(bf16x8 (&d)[4], const char* base, int kb) {
    #pragma unroll
    for (int i = 0; i < 4; ++i) d[i] = *(const bf16x8*)(base + i * 2048 + kb);
}
__device__ __forceinline__ void rdB(bf16x8 (&d)[4], const char* base, int kb) {
    #pragma unroll
    for (int i = 0; i < 4; ++i) d[i] = *(const bf16x8*)(base + i * 2048 + kb);
}
__device__ __forceinline__ void mfma16(f32x4 (&acc)[8][4], int mh,
                                       const bf16x8 (&a)[4], const bf16x8 (&b)[4]) {
    #pragma unroll
    for (int i = 0; i < 4; ++i)
        #pragma unroll
        for (int j = 0; j < 4; ++j)
            acc[mh * 4 + i][j] = __builtin_amdgcn_mfma_f32_16x16x32_bf16(
                a[i], b[j], acc[mh * 4 + i][j], 0, 0, 0);
}

// ---------------- kernel 1: pack A=[x|h], B gate-INTERLEAVED (unchanged) ----
__global__ void pack_kernel(const float* __restrict__ x, const float* __restrict__ h,
                            const float* __restrict__ Wix, const float* __restrict__ Wfx,
                            const float* __restrict__ Wgx, const float* __restrict__ Wox,
                            const float* __restrict__ Wih, const float* __restrict__ Wfh,
                            const float* __restrict__ Wgh, const float* __restrict__ Woh,
                            uint4* __restrict__ Apk, uint4* __restrict__ Bpk)
{
    int t = blockIdx.x * blockDim.x + threadIdx.x;     // 0 .. 2M-1
    const int NCHUNK = (BATCH * K_DIM) / 8;            // 1,048,576 chunks / matrix
    bool isB = t >= NCHUNK;
    int ci = isB ? (t - NCHUNK) : t;

    int cb  = ci & 7;              // 16B chunk within row (8 bf16)
    int row = (ci >> 3) & 127;     // row within 128-row panel
    int kt  = (ci >> 10) & 31;     // K-tile
    int bt  = ci >> 15;            // 128-row panel index, 0..31

    // inverse swizzle: chunk cb of LDS row holds source chunk cb ^ (row&7)
    int k0 = kt * BK + ((cb ^ (row & 7)) << 3);        // source k element, %8==0
    int gr = bt * 128 + row;                           // global m or packed col n'

    const float* src;
    if (!isB) {
        src = (k0 < IN_DIM) ? (x + (size_t)gr * IN_DIM + k0)
                            : (h + (size_t)gr * HS + (k0 - IN_DIM));
    } else {
        int q = (gr >> 4) & 3;                         // gate
        int u = ((gr >> 6) << 4) | (gr & 15);          // unit
        const float* Wq = (k0 < IN_DIM)
            ? ((q == 0) ? Wix : (q == 1) ? Wfx : (q == 2) ? Wgx : Wox)
            : ((q == 0) ? Wih : (q == 1) ? Wfh : (q == 2) ? Wgh : Woh);
        int kk = (k0 < IN_DIM) ? k0 : (k0 - IN_DIM);
        src = Wq + (size_t)u * 1024 + kk;
    }
    float4 v0 = ((const float4*)src)[0];
    float4 v1 = ((const float4*)src)[1];
    uint4 o;
    o.x = pk2(v0.x, v0.y); o.y = pk2(v0.z, v0.w);
    o.z = pk2(v1.x, v1.y); o.w = pk2(v1.z, v1.w);
    (isB ? Bpk : Apk)[ci] = o;
}

// ---------------- kernel 2: fused GEMM + LSTM gates ----------------
// 256x256 tile, 8 waves (2Mx4N). ROLE-SPLIT ANTI-PHASE schedule:
//  - even-role waves (wm=0, one per SIMD): r2 body — reads feed THIS phase's
//    MFMA; BAR; lgkmcnt(0); MFMA; BAR.
//  - odd-role waves (wm=1, the co-resident wave on each SIMD): r5 body —
//    reads feed the NEXT phase; MFMA consumes regs read one phase ago
//    (counted lgkm by scoreboard, no drain).
// Post-barrier each SIMD thus has one wave issuing MFMA immediately and one
// draining LDS -> matrix pipe and LDS port overlap instead of alternating.
// Barriers (2/phase), staging placement, and counted vmcnt are IDENTICAL for
// both roles, so the r2 race proof holds. Odd's cross-tile read (p4) is
// placed AFTER BAR + sched_barrier(0): vmcnt(4)+BAR makes every wave's
// staged shards visible first (vmcnt is per-wave; the barrier globalizes it).
__global__ void __launch_bounds__(512, 2)
gemm_kernel(const char* __restrict__ Apk, const char* __restrict__ Bpk,
            const float* __restrict__ c,
            const float* __restrict__ bix, const float* __restrict__ bfx,
            const float* __restrict__ bgx, const float* __restrict__ box_,
            const float* __restrict__ bih, const float* __restrict__ bfh,
            const float* __restrict__ bgh, const float* __restrict__ boh,
            float* __restrict__ out)
{
    __shared__ uint4 lds4[131072 / 16];                // 128 KiB
    char* lds = (char*)lds4;

    const int tid  = threadIdx.x;
    const int lane = tid & 63;
    const int wid  = tid >> 6;       // 0..7
    const int wm   = wid >> 2;       // 0..1  (also the anti-phase role!)
    const int wn   = wid & 3;        // 0..3
    const int fr   = lane & 15;
    const int kg   = lane >> 4;

    // XCD-aware bijective swizzle: 256 blocks, 8 XCDs, 32 blocks/XCD chunk
    const int phys = blockIdx.x;
    const int virt = (phys & 7) * 32 + (phys >> 3);
    const int bn   = virt & 15;
    const int bm   = virt >> 4;

    const char* gA = Apk + (size_t)(bm * 2) * TPB_BYTES;
    const char* gB = Bpk + (size_t)(bn * 2) * TPB_BYTES;

    // ds_read addressing (swizzle: k-byte ^ ((row&7)<<4); row%8 == fr%8)
    const int kb0 = (kg * 16) ^ ((fr & 7) << 4);
    const int kb1 = kb0 ^ 64;
    const int aB  = wm * HALF_BYTES + fr * 128;     // A: half index == wm
    const int bB  = 32768 + (wn >> 1) * HALF_BYTES + ((wn & 1) * 64 + fr) * 128;

    f32x4 acc[8][4] = {};

    // ---- prologue: tile 0 (A0,A1,B0,B1) + tile 1 (B0,B1) ----
    stage16k(gA + (size_t)(0 * NKT + 0) * HALF_BYTES, lds + 0,     wid, lane);
    stage16k(gA + (size_t)(1 * NKT + 0) * HALF_BYTES, lds + 16384, wid, lane);
    stage16k(gB + (size_t)(0 * NKT + 0) * HALF_BYTES, lds + 32768, wid, lane);
    stage16k(gB + (size_t)(1 * NKT + 0) * HALF_BYTES, lds + 49152, wid, lane);
    stage16k(gB + (size_t)(0 * NKT + 1) * HALF_BYTES, lds + 65536 + 32768, wid, lane);
    stage16k(gB + (size_t)(1 * NKT + 1) * HALF_BYTES, lds + 65536 + 49152, wid, lane);
    VMC(4);                          // tile0 landed; tile1-B in flight
    BAR(); DSB();

    if (wm == 0) {
        // ============ EVEN ROLE: phase-local reads (r2 body, proven) =======
        for (int kt = 0; kt < NKT; ++kt) {
            char* L  = lds + (kt & 1) * 65536;
            char* Ln = lds + ((kt & 1) ^ 1) * 65536;
            const bool s1 = (kt + 1 < NKT), s2 = (kt + 2 < NKT);
            bf16x8 aX[4], aY[4], b0[4], b1[4];

            // p1 (mh0,ks0)
            rdA(aX, L + aB, kb0); rdB(b0, L + bB, kb0);
            if (s1) stage16k(gA + (size_t)(0 * NKT + kt + 1) * HALF_BYTES, Ln + 0, wid, lane);
            BAR(); LGKM0(); PRIO(1); mfma16(acc, 0, aX, b0); PRIO(0); BAR();
            // p2 (mh0,ks1)
            rdA(aY, L + aB, kb1); rdB(b1, L + bB, kb1);
            if (s1) stage16k(gA + (size_t)(1 * NKT + kt + 1) * HALF_BYTES, Ln + 16384, wid, lane);
            BAR(); LGKM0(); PRIO(1); mfma16(acc, 0, aY, b1); PRIO(0); BAR();
            // p3 (mh1,ks0), b0 reused
            rdA(aX, L + aB + 8192, kb0);
            if (s2) stage16k(gB + (size_t)(0 * NKT + kt + 2) * HALF_BYTES, L + 32768, wid, lane);
            BAR(); LGKM0(); PRIO(1); mfma16(acc, 1, aX, b0); PRIO(0); BAR();
            // p4 (mh1,ks1), b1 reused
            rdA(aY, L + aB + 8192, kb1);
            if (s2) stage16k(gB + (size_t)(1 * NKT + kt + 2) * HALF_BYTES, L + 49152, wid, lane);
            if (kt < NKT - 2)       VMC(4);
            else if (kt == NKT - 2) VMC(0);
            BAR(); LGKM0(); PRIO(1); mfma16(acc, 1, aY, b1); PRIO(0); BAR();
        }
    } else {
        // ============ ODD ROLE: read one phase ahead (r5-style) ============
        bf16x8 aU[4], aV[4], b0[4], b1[4];
        rdA(aU, lds + aB, kb0);           // A(t0, mh0, ks0)
        rdB(b0, lds + bB, kb0);           // B(t0, ks0)
        for (int kt = 0; kt < NKT; ++kt) {
            char* L  = lds + (kt & 1) * 65536;
            char* Ln = lds + ((kt & 1) ^ 1) * 65536;
            const bool s1 = (kt + 1 < NKT), s2 = (kt + 2 < NKT);

            // p1: MFMA(mh0,ks0) on aU,b0; read (mh0,ks1)
            if (s1) stage16k(gA + (size_t)(0 * NKT + kt + 1) * HALF_BYTES, Ln + 0, wid, lane);
            rdA(aV, L + aB, kb1); rdB(b1, L + bB, kb1);
            BAR(); PRIO(1); mfma16(acc, 0, aU, b0); PRIO(0); BAR();
            // p2: MFMA(mh0,ks1) on aV,b1; read (mh1,ks0)
            if (s1) stage16k(gA + (size_t)(1 * NKT + kt + 1) * HALF_BYTES, Ln + 16384, wid, lane);
            rdA(aU, L + aB + 8192, kb0);
            BAR(); PRIO(1); mfma16(acc, 0, aV, b1); PRIO(0); BAR();
            // p3: MFMA(mh1,ks0) on aU,b0; read (mh1,ks1)
            if (s2) stage16k(gB + (size_t)(0 * NKT + kt + 2) * HALF_BYTES, L + 32768, wid, lane);
            rdA(aV, L + aB + 8192, kb1);
            BAR(); PRIO(1); mfma16(acc, 1, aU, b0); PRIO(0); BAR();
            // p4: MFMA(mh1,ks1) on aV,b1; cross-tile read AFTER BAR+fence
            if (s2) stage16k(gB + (size_t)(1 * NKT + kt + 2) * HALF_BYTES, L + 49152, wid, lane);
            if (kt < NKT - 2)       VMC(4);
            else if (kt == NKT - 2) VMC(0);
            BAR(); DSB();
            asm volatile("" ::: "memory");     // no ds_read hoist above barrier
            if (s1) { rdA(aU, Ln + aB, kb0); rdB(b0, Ln + bB, kb0); }
            PRIO(1); mfma16(acc, 1, aV, b1); PRIO(0); BAR();
        }
    }

    // ---- fused LSTM epilogue: lane holds all 4 gates of unit u, rows of acc
    const int u  = bn * 64 + wn * 16 + fr;             // unit 0..1023
    const int r0 = bm * 256 + wm * 128;                // batch row base
    const float bi = bix[u] + bih[u];
    const float bf = bfx[u] + bfh[u];
    const float bg = bgx[u] + bgh[u];
    const float bo = box_[u] + boh[u];
    float* hout = out;
    float* cout = out + (size_t)BATCH * HS;

    #pragma unroll
    for (int ai = 0; ai < 8; ++ai) {
        const int rowb = r0 + ai * 16 + kg * 4;
        #pragma unroll
        for (int r = 0; r < 4; ++r) {
            const size_t idx = (size_t)(rowb + r) * HS + u;
            float iv = sigf  (acc[ai][0][r] + bi);
            float fv = sigf  (acc[ai][1][r] + bf);
            float gv = tanhf_(acc[ai][2][r] + bg);
            float ov = sigf  (acc[ai][3][r] + bo);
            float cn = fv * c[idx] + iv * gv;
            hout[idx] = ov * tanhf_(cn);
            cout[idx] = cn;
        }
    }
}

// ---------------- launcher ----------------
extern "C" void kernel_launch(void* const* d_in, const int* in_sizes, int n_in,
                              void* d_out, int out_size, void* d_ws, size_t ws_size,
                              hipStream_t stream)
{
    const float* x   = (const float*)d_in[0];
    const float* h   = (const float*)d_in[1];
    const float* c   = (const float*)d_in[2];
    const float* Wix = (const float*)d_in[3];  const float* bix = (const float*)d_in[4];
    const float* Wfx = (const float*)d_in[5];  const float* bfx = (const float*)d_in[6];
    const float* Wgx = (const float*)d_in[7];  const float* bgx = (const float*)d_in[8];
    const float* Wox = (const float*)d_in[9];  const float* box_ = (const float*)d_in[10];
    const float* Wih = (const float*)d_in[11]; const float* bih = (const float*)d_in[12];
    const float* Wfh = (const float*)d_in[13]; const float* bfh = (const float*)d_in[14];
    const float* Wgh = (const float*)d_in[15]; const float* bgh = (const float*)d_in[16];
    const float* Woh = (const float*)d_in[17]; const float* boh = (const float*)d_in[18];

    char* ws = (char*)d_ws;
    uint4* Apk = (uint4*)ws;                                   // 16 MB
    uint4* Bpk = (uint4*)(ws + (size_t)16 * 1024 * 1024);      // 16 MB

    pack_kernel<<<8192, 256, 0, stream>>>(x, h, Wix, Wfx, Wgx, Wox,
                                          Wih, Wfh, Wgh, Woh, Apk, Bpk);
    gemm_kernel<<<256, 512, 0, stream>>>((const char*)Apk, (const char*)Bpk, c,
                                         bix, bfx, bgx, box_, bih, bfh, bgh, boh,
                                         (float*)d_out);
}